// Round 1
// baseline (502.187 us; speedup 1.0000x reference)
//
#include <hip/hip_runtime.h>
#include <hip/hip_bf16.h>

#ifndef M_PI
#define M_PI 3.14159265358979323846
#endif

// ---------------- workspace layout (float offsets) ----------------
#define OFF_Y1   0ull                      // 1024*4*4096   = 16777216
#define OFF_Y2   16777216ull               // 1024*16*512   =  8388608
#define OFF_Y3   25165824ull               // 1024*32*64    =  2097152
#define OFF_Y4   27262976ull               // 1024*64*8     =   524288
#define OFF_Y5   27787264ull               // 1024*128      =   131072
#define OFF_S    27918336ull               // 1024*512      =   524288
#define OFF_W2G  28442624ull               // 4*27*16       =     1728
#define OFF_W3G  28444352ull               // 16*27*32      =    13824
#define OFF_W5G  28458176ull               // 512*128       =    65536
#define OFF_U    28523712ull               // 64
#define OFF_SP1  28523776ull               // 2*4*64   = 512
#define OFF_SP2  28524288ull               // 2*16*64  = 2048
#define OFF_SP3  28526336ull               // 2*32*64  = 4096
#define OFF_SP4  28530432ull               // 2*64*64  = 8192
#define OFF_SP5  28538624ull               // 2*128*64 = 16384
#define SP_TOTAL 31232

#define BN_EPS 1e-5f

// ---------------- prep: gather weights ----------------
__global__ void k_prep_w(const float* __restrict__ W2, const float* __restrict__ W3,
                         const float* __restrict__ W5,
                         float* __restrict__ w2g, float* __restrict__ w3g,
                         float* __restrict__ w5g) {
    int idx = blockIdx.x * 256 + threadIdx.x;
    if (idx < 1728) {                       // w2g[(ci*27+tap)*16+co]
        int co = idx & 15; int r = idx >> 4; int tap = r % 27; int ci = r / 27;
        w2g[idx] = W2[(co * 4 + ci) * 27 + tap];
        return;
    }
    idx -= 1728;
    if (idx < 13824) {                      // w3g[(ci*27+tap)*32+co]
        int co = idx & 31; int r = idx >> 5; int tap = r % 27; int ci = r / 27;
        w3g[idx] = W3[(co * 16 + ci) * 27 + tap];
        return;
    }
    idx -= 13824;
    if (idx < 65536) {                      // w5g[k*128+co], k=ci*8+dz*4+dy*2+dx
        int co = idx & 127; int k = idx >> 7;
        int dx = k & 1, dy = (k >> 1) & 1, dz = (k >> 2) & 1, ci = k >> 3;
        w5g[idx] = W5[(co * 64 + ci) * 27 + (dz + 1) * 9 + (dy + 1) * 3 + (dx + 1)];
    }
}

// ---------------- prep: u = pe_w @ f1_w (collapses PE branch) ----------------
__global__ void k_prep_u(const float* __restrict__ pe_w, const float* __restrict__ pe_b,
                         const float* __restrict__ f1_w, const float* __restrict__ f1_b,
                         float* __restrict__ u) {
    int t = threadIdx.x;
    if (t < 51) {
        float acc = 0.f;
        for (int j = 0; j < 128; j++) acc += pe_w[t * 128 + j] * f1_w[j];
        u[t] = acc;
    } else if (t == 51) {
        float acc = f1_b[0];
        for (int j = 0; j < 128; j++) acc += pe_b[j] * f1_w[j];
        u[51] = acc;
    }
}

// ---------------- PE scores: s[b,n] = emb . u + c0 ----------------
__global__ __launch_bounds__(256) void k_pe(const float* __restrict__ centers,
                                            const float* __restrict__ u,
                                            float* __restrict__ s) {
    __shared__ float us[52];
    int t = threadIdx.x;
    if (t < 52) us[t] = u[t];
    __syncthreads();
    int idx = blockIdx.x * 256 + t;         // < 524288
    float c3[3];
    c3[0] = centers[idx * 3 + 0];
    c3[1] = centers[idx * 3 + 1];
    c3[2] = centers[idx * 3 + 2];
    float acc = us[51] + c3[0] * us[48] + c3[1] * us[49] + c3[2] * us[50];
#pragma unroll
    for (int a = 0; a < 3; a++) {
#pragma unroll
        for (int f = 0; f < 8; f++) {
            float ang = c3[a] * (float)(M_PI * (double)(1 << f));
            float sv, cv;
            sincosf(ang, &sv, &cv);
            acc += sv * us[a * 8 + f] + cv * us[24 + a * 8 + f];
        }
    }
    s[idx] = acc;
}

// ---------------- conv1: [1,32^3] -> [4,16^3], raw out + stats ----------------
__global__ __launch_bounds__(256) void k_c1(const float* __restrict__ vox,
                                            const float* __restrict__ W1,
                                            const float* __restrict__ b1,
                                            float* __restrict__ y1,
                                            float* __restrict__ sp1) {
    __shared__ float slab[9 * 32 * 33];     // [p][y][x pad33]
    __shared__ float wl[27 * 4];            // [tap][co]
    int bid = blockIdx.x;
    int b = bid >> 2, zq = bid & 3;
    int t = threadIdx.x;
    int xo = t & 15, yo = t >> 4;
    if (t < 108) { int tap = t >> 2, co = t & 3; wl[t] = W1[co * 27 + tap]; }
    int zb = 8 * zq - 1;
    const float* vb = vox + (size_t)b * 32768;
    for (int p = 0; p < 9; p++) {
        int zi = zb + p;
        float4 v = make_float4(0.f, 0.f, 0.f, 0.f);
        if (zi >= 0) v = *(const float4*)(vb + zi * 1024 + t * 4);
        int y = t >> 3, x = (t & 7) * 4;
        float* dst = slab + p * 1056 + y * 33 + x;
        dst[0] = v.x; dst[1] = v.y; dst[2] = v.z; dst[3] = v.w;
    }
    __syncthreads();
    float acc[4][4];
#pragma unroll
    for (int z = 0; z < 4; z++)
#pragma unroll
        for (int c = 0; c < 4; c++) acc[z][c] = b1[c];
    for (int kz = 0; kz < 3; kz++)
        for (int ky = 0; ky < 3; ky++) {
            int yi = 2 * yo + ky - 1;
            if (yi < 0) continue;
#pragma unroll
            for (int kx = 0; kx < 3; kx++) {
                int xi = 2 * xo + kx - 1;
                if (xi < 0) continue;
                float4 w = *(const float4*)(wl + (kz * 9 + ky * 3 + kx) * 4);
#pragma unroll
                for (int z = 0; z < 4; z++) {
                    float v = slab[(2 * z + kz) * 1056 + yi * 33 + xi];
                    acc[z][0] += v * w.x; acc[z][1] += v * w.y;
                    acc[z][2] += v * w.z; acc[z][3] += v * w.w;
                }
            }
        }
    size_t base = (size_t)b * 16384;
    float sums[4], sqs[4];
#pragma unroll
    for (int c = 0; c < 4; c++) { sums[c] = 0.f; sqs[c] = 0.f; }
#pragma unroll
    for (int c = 0; c < 4; c++)
#pragma unroll
        for (int z = 0; z < 4; z++) {
            float v = acc[z][c];
            y1[base + c * 4096 + (zq * 4 + z) * 256 + yo * 16 + xo] = v;
            sums[c] += v; sqs[c] += v * v;
        }
    int slot = bid & 63;
#pragma unroll
    for (int c = 0; c < 4; c++) {
        float s_ = sums[c], q_ = sqs[c];
        for (int m = 32; m; m >>= 1) { s_ += __shfl_xor(s_, m, 64); q_ += __shfl_xor(q_, m, 64); }
        if ((t & 63) == 0) {
            atomicAdd(&sp1[(2 * c + 0) * 64 + slot], s_);
            atomicAdd(&sp1[(2 * c + 1) * 64 + slot], q_);
        }
    }
}

// ---------------- conv2: bn1+relu(y1) -> [16,8^3] ----------------
__global__ __launch_bounds__(512) void k_c2(const float* __restrict__ y1,
                                            const float* __restrict__ w2g,
                                            const float* __restrict__ b2,
                                            const float* __restrict__ g1,
                                            const float* __restrict__ be1,
                                            const float* __restrict__ sp1,
                                            float* __restrict__ y2,
                                            float* __restrict__ sp2) {
    __shared__ float in2[4 * 4352];         // ci*4352 + z*272 + y*17 + x
    __shared__ float wl[1728];
    __shared__ float ad[8];
    __shared__ float red[8];
    int t = threadIdx.x;
    int b = blockIdx.x;
    {
        int w0 = t >> 6, lane = t & 63;     // 8 rows exactly
        float v = sp1[w0 * 64 + lane];
        for (int m = 32; m; m >>= 1) v += __shfl_xor(v, m, 64);
        if (lane == 0) red[w0] = v;
    }
    __syncthreads();
    if (t < 4) {
        float cnt = 4194304.0f;
        float m = red[2 * t] / cnt;
        float var = red[2 * t + 1] / cnt - m * m;
        float a = g1[t] * rsqrtf(var + BN_EPS);
        ad[t] = a; ad[4 + t] = be1[t] - m * a;
    }
    for (int i = t; i < 1728; i += 512) wl[i] = w2g[i];
    __syncthreads();
    const float* yb = y1 + (size_t)b * 16384;
    for (int i = 0; i < 8; i++) {
        int e4 = t + i * 512;
        float4 v = *(const float4*)(yb + e4 * 4);
        int ci = e4 >> 10;
        int z = (e4 >> 6) & 15;
        int r = (e4 & 63) * 4;
        int y = r >> 4, x = r & 15;
        float a = ad[ci], d = ad[4 + ci];
        float* dst = in2 + ci * 4352 + z * 272 + y * 17 + x;
        dst[0] = fmaxf(a * v.x + d, 0.f);
        dst[1] = fmaxf(a * v.y + d, 0.f);
        dst[2] = fmaxf(a * v.z + d, 0.f);
        dst[3] = fmaxf(a * v.w + d, 0.f);
    }
    __syncthreads();
    int zo = t >> 6;                        // wave -> z-plane
    int lane = t & 63;
    int yo = lane >> 3, xo = lane & 7;
    float acc[16];
#pragma unroll
    for (int c = 0; c < 16; c++) acc[c] = b2[c];
    for (int ci = 0; ci < 4; ci++)
        for (int kz = 0; kz < 3; kz++) {
            int zi = 2 * zo + kz - 1;
            if (zi < 0) continue;
            const float* inz = in2 + ci * 4352 + zi * 272;
            for (int ky = 0; ky < 3; ky++) {
                int yi = 2 * yo + ky - 1;
                if (yi < 0) continue;
                const float* iny = inz + yi * 17;
#pragma unroll
                for (int kx = 0; kx < 3; kx++) {
                    int xi = 2 * xo + kx - 1;
                    if (xi < 0) continue;
                    float v = iny[xi];
                    const float* wp = wl + (ci * 27 + kz * 9 + ky * 3 + kx) * 16;
#pragma unroll
                    for (int c = 0; c < 16; c++) acc[c] += v * wp[c];
                }
            }
        }
    size_t ob = (size_t)b * 8192 + zo * 64 + yo * 8 + xo;
#pragma unroll
    for (int c = 0; c < 16; c++) y2[ob + c * 512] = acc[c];
    int slot = b & 63;
#pragma unroll
    for (int c = 0; c < 16; c++) {
        float s_ = acc[c], q_ = acc[c] * acc[c];
        for (int m = 32; m; m >>= 1) { s_ += __shfl_xor(s_, m, 64); q_ += __shfl_xor(q_, m, 64); }
        if (lane == 0) {
            atomicAdd(&sp2[(2 * c + 0) * 64 + slot], s_);
            atomicAdd(&sp2[(2 * c + 1) * 64 + slot], q_);
        }
    }
}

// ---------------- conv3: bn2+relu(y2) -> [32,4^3], 2 b per block ----------------
__global__ __launch_bounds__(512) void k_c3(const float* __restrict__ y2,
                                            const float* __restrict__ w3g,
                                            const float* __restrict__ b3,
                                            const float* __restrict__ g2,
                                            const float* __restrict__ be2,
                                            const float* __restrict__ sp2,
                                            float* __restrict__ y3,
                                            float* __restrict__ sp3) {
    __shared__ float in3[2 * 9216];         // per b: ci*576 + z*72 + y*9 + x
    __shared__ float wl[13824];
    __shared__ float ad[32];
    __shared__ float red[32];
    int t = threadIdx.x;
    int bp = blockIdx.x;
    {
        int w0 = t >> 6, lane = t & 63;
        for (int row = w0; row < 32; row += 8) {
            float v = sp2[row * 64 + lane];
            for (int m = 32; m; m >>= 1) v += __shfl_xor(v, m, 64);
            if (lane == 0) red[row] = v;
        }
    }
    __syncthreads();
    if (t < 16) {
        float cnt = 524288.0f;
        float m = red[2 * t] / cnt;
        float var = red[2 * t + 1] / cnt - m * m;
        float a = g2[t] * rsqrtf(var + BN_EPS);
        ad[t] = a; ad[16 + t] = be2[t] - m * a;
    }
    for (int i = t; i < 13824; i += 512) wl[i] = w3g[i];
    __syncthreads();
    {
        int bh = t >> 8, tl = t & 255;
        const float* yb = y2 + (size_t)(bp * 2 + bh) * 8192;
        float* inb = in3 + bh * 9216;
        for (int i = 0; i < 8; i++) {
            int e4 = tl + i * 256;
            float4 v = *(const float4*)(yb + e4 * 4);
            int ci = e4 >> 7;
            int z = (e4 >> 4) & 7;
            int r = (e4 & 15) * 4;
            int y = r >> 3, x = r & 7;
            float a = ad[ci], d = ad[16 + ci];
            float* dst = inb + ci * 576 + z * 72 + y * 9 + x;
            dst[0] = fmaxf(a * v.x + d, 0.f);
            dst[1] = fmaxf(a * v.y + d, 0.f);
            dst[2] = fmaxf(a * v.z + d, 0.f);
            dst[3] = fmaxf(a * v.w + d, 0.f);
        }
    }
    __syncthreads();
    int w0 = t >> 6, lane = t & 63;
    int cbh = w0 >> 2, cog = w0 & 3;
    int zo = lane >> 4, yo = (lane >> 2) & 3, xo = lane & 3;
    const float* inq = in3 + cbh * 9216;
    float acc[8];
#pragma unroll
    for (int c = 0; c < 8; c++) acc[c] = b3[cog * 8 + c];
    for (int ci = 0; ci < 16; ci++)
        for (int kz = 0; kz < 3; kz++) {
            int zi = 2 * zo + kz - 1;
            if (zi < 0) continue;
            const float* inz = inq + ci * 576 + zi * 72;
            for (int ky = 0; ky < 3; ky++) {
                int yi = 2 * yo + ky - 1;
                if (yi < 0) continue;
                const float* iny = inz + yi * 9;
#pragma unroll
                for (int kx = 0; kx < 3; kx++) {
                    int xi = 2 * xo + kx - 1;
                    if (xi < 0) continue;
                    float v = iny[xi];
                    const float* wp = wl + (ci * 27 + kz * 9 + ky * 3 + kx) * 32 + cog * 8;
#pragma unroll
                    for (int c = 0; c < 8; c++) acc[c] += v * wp[c];
                }
            }
        }
    int b = bp * 2 + cbh;
    size_t ob = (size_t)b * 2048 + zo * 16 + yo * 4 + xo;
#pragma unroll
    for (int c = 0; c < 8; c++) y3[ob + (size_t)(cog * 8 + c) * 64] = acc[c];
    int slot = b & 63;
#pragma unroll
    for (int c = 0; c < 8; c++) {
        float s_ = acc[c], q_ = acc[c] * acc[c];
        for (int m = 32; m; m >>= 1) { s_ += __shfl_xor(s_, m, 64); q_ += __shfl_xor(q_, m, 64); }
        if (lane == 0) {
            int co = cog * 8 + c;
            atomicAdd(&sp3[(2 * co + 0) * 64 + slot], s_);
            atomicAdd(&sp3[(2 * co + 1) * 64 + slot], q_);
        }
    }
}

// ---------------- conv4: bn3+relu(y3) -> [64,2^3]; block = (4 b, 16 co) ----------------
__global__ __launch_bounds__(256) void k_c4(const float* __restrict__ y3,
                                            const float* __restrict__ W4,
                                            const float* __restrict__ b4,
                                            const float* __restrict__ g3,
                                            const float* __restrict__ be3,
                                            const float* __restrict__ sp3,
                                            float* __restrict__ y4,
                                            float* __restrict__ sp4) {
    __shared__ float in4[4 * 2208];         // per b: ci*69 + z*17 + y*4 + x
    __shared__ float wl[13824];             // [16co][32ci][27]
    __shared__ float ad[64];
    __shared__ float red[64];
    int t = threadIdx.x;
    int bid = blockIdx.x;
    int bq = bid >> 2, coq = bid & 3;
    {
        int w0 = t >> 6, lane = t & 63;
        for (int row = w0; row < 64; row += 4) {
            float v = sp3[row * 64 + lane];
            for (int m = 32; m; m >>= 1) v += __shfl_xor(v, m, 64);
            if (lane == 0) red[row] = v;
        }
    }
    __syncthreads();
    if (t < 32) {
        float cnt = 65536.0f;
        float m = red[2 * t] / cnt;
        float var = red[2 * t + 1] / cnt - m * m;
        float a = g3[t] * rsqrtf(var + BN_EPS);
        ad[t] = a; ad[32 + t] = be3[t] - m * a;
    }
    for (int i = t; i < 13824; i += 256) wl[i] = W4[coq * 13824 + i];
    __syncthreads();
    int w0 = t >> 6, lane = t & 63;
    int b = bq * 4 + w0;
    {
        const float* yb = y3 + (size_t)b * 2048;
        float* inb = in4 + w0 * 2208;
        for (int i = 0; i < 8; i++) {
            int e4 = lane + i * 64;
            float4 v = *(const float4*)(yb + e4 * 4);
            int ci = e4 >> 4;
            int z = (e4 >> 2) & 3;
            int r = (e4 & 3) * 4;
            int y = r >> 2, x = r & 3;
            float a = ad[ci], d = ad[32 + ci];
            float* dst = inb + ci * 69 + z * 17 + y * 4 + x;
            dst[0] = fmaxf(a * v.x + d, 0.f);
            dst[1] = fmaxf(a * v.y + d, 0.f);
            dst[2] = fmaxf(a * v.z + d, 0.f);
            dst[3] = fmaxf(a * v.w + d, 0.f);
        }
    }
    __syncthreads();
    int cisub = lane >> 3;
    int pos = lane & 7;
    int pz = pos >> 2, py = (pos >> 1) & 1, px = pos & 1;
    const float* inb = in4 + w0 * 2208;
    float acc[16];
#pragma unroll
    for (int c = 0; c < 16; c++) acc[c] = 0.f;
    for (int cii = 0; cii < 4; cii++) {
        int ci = cisub * 4 + cii;
        const float* inc = inb + ci * 69;
        for (int kz = 0; kz < 3; kz++) {
            int zi = 2 * pz + kz - 1;
            if (zi < 0) continue;
            for (int ky = 0; ky < 3; ky++) {
                int yi = 2 * py + ky - 1;
                if (yi < 0) continue;
#pragma unroll
                for (int kx = 0; kx < 3; kx++) {
                    int xi = 2 * px + kx - 1;
                    if (xi < 0) continue;
                    float v = inc[zi * 17 + yi * 4 + xi];
                    const float* wp = wl + ci * 27 + kz * 9 + ky * 3 + kx;
#pragma unroll
                    for (int c = 0; c < 16; c++) acc[c] += v * wp[c * 864];
                }
            }
        }
    }
#pragma unroll
    for (int c = 0; c < 16; c++) {
        float v = acc[c];
        v += __shfl_xor(v, 8, 64);
        v += __shfl_xor(v, 16, 64);
        v += __shfl_xor(v, 32, 64);
        acc[c] = v;
    }
    if (cisub == 0) {
        size_t ob = (size_t)b * 512 + pos;
#pragma unroll
        for (int c = 0; c < 16; c++) {
            int co = coq * 16 + c;
            float v = acc[c] + b4[co];
            y4[ob + co * 8] = v;
            acc[c] = v;
        }
        int slot = bid & 63;
#pragma unroll
        for (int c = 0; c < 16; c++) {
            float s_ = acc[c], q_ = acc[c] * acc[c];
            s_ += __shfl_xor(s_, 1, 64); q_ += __shfl_xor(q_, 1, 64);
            s_ += __shfl_xor(s_, 2, 64); q_ += __shfl_xor(q_, 2, 64);
            s_ += __shfl_xor(s_, 4, 64); q_ += __shfl_xor(q_, 4, 64);
            if (pos == 0) {
                int co = coq * 16 + c;
                atomicAdd(&sp4[(2 * co + 0) * 64 + slot], s_);
                atomicAdd(&sp4[(2 * co + 1) * 64 + slot], q_);
            }
        }
    }
}

// ---------------- conv5 as GEMM: [1024,512](bn4relu) @ w5g[512,128] ----------------
__global__ __launch_bounds__(256) void k_c5(const float* __restrict__ y4,
                                            const float* __restrict__ w5g,
                                            const float* __restrict__ b5,
                                            const float* __restrict__ g4,
                                            const float* __restrict__ be4,
                                            const float* __restrict__ sp4,
                                            float* __restrict__ y5,
                                            float* __restrict__ sp5) {
    __shared__ float A[4 * 512];
    __shared__ float ad[128];
    __shared__ float red[128];
    int t = threadIdx.x;
    int bq = blockIdx.x;                    // 4 b per block
    {
        int w0 = t >> 6, lane = t & 63;
        for (int row = w0; row < 128; row += 4) {
            float v = sp4[row * 64 + lane];
            for (int m = 32; m; m >>= 1) v += __shfl_xor(v, m, 64);
            if (lane == 0) red[row] = v;
        }
    }
    __syncthreads();
    if (t < 64) {
        float cnt = 8192.0f;
        float m = red[2 * t] / cnt;
        float var = red[2 * t + 1] / cnt - m * m;
        float a = g4[t] * rsqrtf(var + BN_EPS);
        ad[t] = a; ad[64 + t] = be4[t] - m * a;
    }
    __syncthreads();
    for (int i = 0; i < 8; i++) {
        int e = t + i * 256;
        int k = e & 511;
        int ci = k >> 3;
        float v = y4[(size_t)bq * 2048 + e];
        A[e] = fmaxf(ad[ci] * v + ad[64 + ci], 0.f);
    }
    __syncthreads();
    int co = t & 127, bh = t >> 7;
    float acc0 = b5[co], acc1 = b5[co];
    const float* Ab = A + bh * 1024;
    for (int k = 0; k < 512; k++) {
        float wv = w5g[k * 128 + co];
        acc0 += Ab[k] * wv;
        acc1 += Ab[512 + k] * wv;
    }
    int b0 = bq * 4 + bh * 2;
    y5[(size_t)b0 * 128 + co] = acc0;
    y5[(size_t)(b0 + 1) * 128 + co] = acc1;
    int slot = bq & 63;
    atomicAdd(&sp5[(2 * co + 0) * 64 + slot], acc0 + acc1);
    atomicAdd(&sp5[(2 * co + 1) * 64 + slot], acc0 * acc0 + acc1 * acc1);
}

// ---------------- final: out = s @ f2_w + f2_b + relu(bn5(y5)) ----------------
__global__ __launch_bounds__(256) void k_f2(const float* __restrict__ s,
                                            const float* __restrict__ f2w,
                                            const float* __restrict__ f2b,
                                            const float* __restrict__ g5,
                                            const float* __restrict__ be5,
                                            const float* __restrict__ sp5,
                                            const float* __restrict__ y5,
                                            float* __restrict__ out) {
    __shared__ float A[4 * 512];
    __shared__ float ad[256];
    __shared__ float red[256];
    int t = threadIdx.x;
    int bq = blockIdx.x;
    {
        int w0 = t >> 6, lane = t & 63;
        for (int row = w0; row < 256; row += 4) {
            float v = sp5[row * 64 + lane];
            for (int m = 32; m; m >>= 1) v += __shfl_xor(v, m, 64);
            if (lane == 0) red[row] = v;
        }
    }
    __syncthreads();
    if (t < 128) {
        float cnt = 1024.0f;
        float m = red[2 * t] / cnt;
        float var = red[2 * t + 1] / cnt - m * m;
        float a = g5[t] * rsqrtf(var + BN_EPS);
        ad[t] = a; ad[128 + t] = be5[t] - m * a;
    }
    for (int i = 0; i < 8; i++) {
        int e = t + i * 256;
        A[e] = s[(size_t)bq * 2048 + e];
    }
    __syncthreads();
    int co = t & 127, bh = t >> 7;
    float acc0 = f2b[co], acc1 = f2b[co];
    const float* Ab = A + bh * 1024;
    for (int k = 0; k < 512; k++) {
        float wv = f2w[k * 128 + co];
        acc0 += Ab[k] * wv;
        acc1 += Ab[512 + k] * wv;
    }
    int b0 = bq * 4 + bh * 2;
    float v0 = y5[(size_t)b0 * 128 + co];
    float v1 = y5[(size_t)(b0 + 1) * 128 + co];
    out[(size_t)b0 * 128 + co] = acc0 + fmaxf(ad[co] * v0 + ad[128 + co], 0.f);
    out[(size_t)(b0 + 1) * 128 + co] = acc1 + fmaxf(ad[co] * v1 + ad[128 + co], 0.f);
}

extern "C" void kernel_launch(void* const* d_in, const int* in_sizes, int n_in,
                              void* d_out, int out_size, void* d_ws, size_t ws_size,
                              hipStream_t stream) {
    const float* vox     = (const float*)d_in[0];
    const float* centers = (const float*)d_in[1];
    const float* W1   = (const float*)d_in[2];
    const float* b1   = (const float*)d_in[3];
    const float* g1   = (const float*)d_in[4];
    const float* be1  = (const float*)d_in[5];
    const float* W2   = (const float*)d_in[6];
    const float* b2   = (const float*)d_in[7];
    const float* g2   = (const float*)d_in[8];
    const float* be2  = (const float*)d_in[9];
    const float* W3   = (const float*)d_in[10];
    const float* b3   = (const float*)d_in[11];
    const float* g3   = (const float*)d_in[12];
    const float* be3  = (const float*)d_in[13];
    const float* W4   = (const float*)d_in[14];
    const float* b4   = (const float*)d_in[15];
    const float* g4   = (const float*)d_in[16];
    const float* be4  = (const float*)d_in[17];
    const float* W5   = (const float*)d_in[18];
    const float* b5   = (const float*)d_in[19];
    const float* g5   = (const float*)d_in[20];
    const float* be5  = (const float*)d_in[21];
    const float* pe_w = (const float*)d_in[22];
    const float* pe_b = (const float*)d_in[23];
    const float* f1_w = (const float*)d_in[24];
    const float* f1_b = (const float*)d_in[25];
    const float* f2_w = (const float*)d_in[26];
    const float* f2_b = (const float*)d_in[27];

    float* ws  = (float*)d_ws;
    float* y1  = ws + OFF_Y1;
    float* y2  = ws + OFF_Y2;
    float* y3  = ws + OFF_Y3;
    float* y4  = ws + OFF_Y4;
    float* y5  = ws + OFF_Y5;
    float* s   = ws + OFF_S;
    float* w2g = ws + OFF_W2G;
    float* w3g = ws + OFF_W3G;
    float* w5g = ws + OFF_W5G;
    float* u   = ws + OFF_U;
    float* sp1 = ws + OFF_SP1;
    float* sp2 = ws + OFF_SP2;
    float* sp3 = ws + OFF_SP3;
    float* sp4 = ws + OFF_SP4;
    float* sp5 = ws + OFF_SP5;

    hipMemsetAsync((void*)sp1, 0, SP_TOTAL * sizeof(float), stream);
    k_prep_w<<<317, 256, 0, stream>>>(W2, W3, W5, w2g, w3g, w5g);
    k_prep_u<<<1, 64, 0, stream>>>(pe_w, pe_b, f1_w, f1_b, u);
    k_pe<<<2048, 256, 0, stream>>>(centers, u, s);
    k_c1<<<4096, 256, 0, stream>>>(vox, W1, b1, y1, sp1);
    k_c2<<<1024, 512, 0, stream>>>(y1, w2g, b2, g1, be1, sp1, y2, sp2);
    k_c3<<<512, 512, 0, stream>>>(y2, w3g, b3, g2, be2, sp2, y3, sp3);
    k_c4<<<1024, 256, 0, stream>>>(y3, W4, b4, g3, be3, sp3, y4, sp4);
    k_c5<<<256, 256, 0, stream>>>(y4, w5g, b5, g4, be4, sp4, y5, sp5);
    k_f2<<<256, 256, 0, stream>>>(s, f2_w, f2_b, g5, be5, sp5, y5, (float*)d_out);
}